// Round 11
// baseline (168.047 us; speedup 1.0000x reference)
//
#include <hip/hip_runtime.h>
#include <math.h>

#define B_ 512
#define T_ 256
#define I_ 7
#define H_ 64
#define LC_ 32
#define NC_ (T_ / LC_)   // 8 chunks
#define L2E 1.44269504089f
#define GUARD2 (-21.64f)

typedef short bf16x8 __attribute__((ext_vector_type(8)));
typedef short short4v __attribute__((ext_vector_type(4)));
typedef float f32x4 __attribute__((ext_vector_type(4)));

__device__ __forceinline__ unsigned short f2bf(float f) {
  unsigned u = __float_as_uint(f);
  u += 0x7fff + ((u >> 16) & 1);          // RNE
  return (unsigned short)(u >> 16);
}
__device__ __forceinline__ float bf2f(unsigned short u) {
  return __uint_as_float(((unsigned)u) << 16);
}
__device__ __forceinline__ float ex2(float x) { return __builtin_amdgcn_exp2f(x); }
__device__ __forceinline__ float lg2(float x) { return __builtin_amdgcn_logf(x); }
// log2(sigmoid(a)) given a already scaled by log2e
__device__ __forceinline__ float logsig2(float a2) {
  return (a2 < GUARD2) ? a2 : -lg2(1.f + ex2(-a2));
}
__device__ __forceinline__ float sig2(float a2) {
  return __fdividef(1.f, 1.f + ex2(-a2));
}

// ---- consumers: v-pack, rows = lane, t in [vt0, vt0+8) ----
#define PACK_V32(C) do {                                                      \
  const float* xp_ = xb + (C) * (LC_ * I_);                                   \
  unsigned short vv[8];                                                       \
  _Pragma("unroll") for (int tt = 0; tt < 8; ++tt) {                          \
    const int t = vt0 + tt;                                                   \
    float vp = bV;                                                            \
    _Pragma("unroll") for (int jj = 0; jj < 7; ++jj)                          \
      vp = fmaf(xp_[t * 7 + jj], wVl[jj], vp);                                \
    vv[tt] = f2bf(vp);                                                        \
  }                                                                           \
  short4v p0 = {(short)vv[0], (short)vv[1], (short)vv[2], (short)vv[3]};      \
  short4v p1 = {(short)vv[4], (short)vv[5], (short)vv[6], (short)vv[7]};      \
  *(short4v*)&sVT[(C) & 1][lane][vt0]     = p0;                               \
  *(short4v*)&sVT[(C) & 1][lane][vt0 + 4] = p1;                               \
} while (0)

// ---- w4/w5: i*k preacts -> sIK (bf16), t-half tb..tb+15 ----
#define IK_PRE32(C) do {                                                      \
  const float* xp_ = xb + (C) * (LC_ * I_);                                   \
  _Pragma("unroll") for (int tt = 0; tt < 16; ++tt) {                         \
    const int t = tb + tt;                                                    \
    float xs[7];                                                              \
    _Pragma("unroll") for (int jj = 0; jj < 7; ++jj) xs[jj] = xp_[t * 7 + jj];\
    float ip = bI2, kp = bK;                                                  \
    _Pragma("unroll") for (int jj = 0; jj < 7; ++jj) {                        \
      ip = fmaf(xs[jj], wi2[jj], ip);                                         \
      kp = fmaf(xs[jj], wk[jj], kp);                                          \
    }                                                                         \
    sIK[(C) & 1][t][lane] = f2bf(ex2(ip) * kp * 0.125f);                      \
  }                                                                           \
} while (0)

// ---- w4/w5: k~ = ik*2^{m-cl}, k^ = k~*2^{cl31-m}; prefix from bf16 sLs ----
#define IK_EXP32(C) do {                                                      \
  float cl[32];                                                               \
  _Pragma("unroll") for (int t = 0; t < 32; ++t)                              \
    cl[t] = bf2f(sLs[(C) & 1][t][lane]);                                      \
  _Pragma("unroll") for (int t = 1; t < 32; ++t) cl[t] += cl[t - 1];          \
  const float m = cl[15];                                                     \
  const float scl = ex2(cl[31] - m);                                          \
  unsigned short kh[16];                                                      \
  _Pragma("unroll") for (int tt = 0; tt < 16; ++tt) {                         \
    const int t = tb + tt;                                                    \
    const float ik = bf2f(sIK[(C) & 1][t][lane]);                             \
    const float u = ik * ex2(m - cl[t]);                                      \
    sKt[(C) & 1][t][lane] = f2bf(u);                                          \
    kh[tt] = f2bf(u * scl);                                                   \
  }                                                                           \
  _Pragma("unroll") for (int g = 0; g < 4; ++g) {                             \
    short4v pk = {(short)kh[4 * g], (short)kh[4 * g + 1],                     \
                  (short)kh[4 * g + 2], (short)kh[4 * g + 3]};                \
    *(short4v*)&sKnT[(C) & 1][lane][tb + 4 * g] = pk;                         \
  }                                                                           \
} while (0)

// ---- w6/w7: f-gate half (t = ftb..ftb+15) -> bf16 sLs ----
#define F_HALF32(C) do {                                                      \
  const float* xp_ = xb + (C) * (LC_ * I_);                                   \
  _Pragma("unroll") for (int tt = 0; tt < 16; ++tt) {                         \
    const int t = ftb + tt;                                                   \
    float fp = bF2;                                                           \
    _Pragma("unroll") for (int jj = 0; jj < 7; ++jj)                          \
      fp = fmaf(xp_[t * 7 + jj], wf2[jj], fp);                                \
    sLs[(C) & 1][t][lane] = f2bf(logsig2(fp));                                \
  }                                                                           \
} while (0)

// ---- w6: chunk scalars (2^{cl15}, 2^{cl31}) + q~ t0-15 ----
#define SCALQ32(C) do {                                                       \
  const float* xp_ = xb + (C) * (LC_ * I_);                                   \
  float cl[32];                                                               \
  _Pragma("unroll") for (int t = 0; t < 32; ++t)                              \
    cl[t] = bf2f(sLs[(C) & 1][t][lane]);                                      \
  _Pragma("unroll") for (int t = 1; t < 32; ++t) cl[t] += cl[t - 1];          \
  const float m = cl[15];                                                     \
  sEM[(C) & 1][lane]   = ex2(m);                                              \
  sFtot[(C) & 1][lane] = ex2(cl[31]);                                         \
  _Pragma("unroll") for (int t = 0; t < 16; ++t) {                            \
    float qq = bQ;                                                            \
    _Pragma("unroll") for (int jj = 0; jj < 7; ++jj)                          \
      qq = fmaf(xp_[t * 7 + jj], wq[jj], qq);                                 \
    sQt[(C) & 1][t][lane] = f2bf(qq * ex2(cl[t] - m));                        \
  }                                                                           \
} while (0)

// ---- w7: q~ t16-31 + Sq (lanes < 32) ----
#define SQQ32(C) do {                                                         \
  const float* xp_ = xb + (C) * (LC_ * I_);                                   \
  float cl[32];                                                               \
  _Pragma("unroll") for (int t = 0; t < 32; ++t)                              \
    cl[t] = bf2f(sLs[(C) & 1][t][lane]);                                      \
  _Pragma("unroll") for (int t = 1; t < 32; ++t) cl[t] += cl[t - 1];          \
  const float m = cl[15];                                                     \
  _Pragma("unroll") for (int t = 16; t < 32; ++t) {                           \
    float qq = bQ;                                                            \
    _Pragma("unroll") for (int jj = 0; jj < 7; ++jj)                          \
      qq = fmaf(xp_[t * 7 + jj], wq[jj], qq);                                 \
    sQt[(C) & 1][t][lane] = f2bf(qq * ex2(cl[t] - m));                        \
  }                                                                           \
  if (lane < 32) {                                                            \
    float Sqv = wqs[7];                                                       \
    _Pragma("unroll") for (int jj = 0; jj < 7; ++jj)                          \
      Sqv = fmaf(xp_[lane * 7 + jj], wqs[jj], Sqv);                           \
    sSq[(C) & 1][lane] = Sqv;                                                 \
  }                                                                           \
} while (0)

// L=32 chunkwise mLSTM, R9-proven 2-barrier split, 19 regions (was 33).
// Region A(j): w0-3 den-scan(j, own ch) + shared-S(j) (waves 0/2/3, one tile
//   each; tile (0,1) all-masked, stays zero) + C0 snapshot/decay/G(j) +
//   v-pack(j+1).  w4/5: IK_PRE(j+1).  w6/7: F-half(j+1).
// Region B(j): w0-3 Num(j) (2 t-tiles; sS read crosses B1) + o-proj + h(j).
//   w4/5: IK_EXP(j+1).  w6: scalars+q~lo(j+1).  w7: q~hi+Sq(j+1).
// sLs/sIK bf16 (all readers derive prefixes from the SAME bf16 values ->
// num/den stay mutually consistent). sS/sC0 single-buffered (A->B crosses the
// barrier; rewrite next A crosses B2). All 2-buffered parities audited.
// sS fully zeroed once (bf16 junk can be NaN; NaN*0=NaN through MFMA -- R4).
// Per-role divergent barrier loops (unified union spills -> scratch, R8).
__global__ __launch_bounds__(512, 4) void mlstm32(
    const float* __restrict__ x,
    const float* __restrict__ Cin,
    const float* __restrict__ nin,
    const float* __restrict__ Wq, const float* __restrict__ bq,
    const float* __restrict__ Wk, const float* __restrict__ bk,
    const float* __restrict__ Wv, const float* __restrict__ bv,
    const float* __restrict__ Wi, const float* __restrict__ bi,
    const float* __restrict__ Wf, const float* __restrict__ bf,
    const float* __restrict__ Wo, const float* __restrict__ bo,
    float* __restrict__ hout, float* __restrict__ Cout, float* __restrict__ nout)
{
  const int b    = blockIdx.x;
  const int tid  = threadIdx.x;
  const int lane = tid & 63;
  const int w    = __builtin_amdgcn_readfirstlane(tid >> 6);  // wave 0..7
  const int quad = lane >> 4;
  const int sl   = lane & 15;

  __shared__ __align__(16) unsigned short sQt[2][LC_][72];   // q~ [t][c]
  __shared__ __align__(16) unsigned short sKt[2][LC_][72];   // k~ [s][c]
  __shared__ __align__(16) unsigned short sKnT[2][H_][40];   // k^T [c][s]
  __shared__ __align__(16) unsigned short sVT[2][H_][40];    // v [r][s]
  __shared__ __align__(16) unsigned short sS[LC_][40];       // shared masked S [t][s]
  __shared__ __align__(16) unsigned short sC0[H_][72];       // C0*2^m [r][c]
  __shared__ unsigned short sLs[2][LC_][66];  // bf16 log2(sigmoid(f)) [t][c]
  __shared__ unsigned short sIK[2][LC_][66];  // bf16 i*k (scaled) [t][c]
  __shared__ float sSq[2][LC_];               // sum_r q_t[r]
  __shared__ float sEM[2][H_];                // 2^{cl15}
  __shared__ float sFtot[2][H_];              // 2^{cl31}
  __shared__ float sNv[H_];

  // zero ALL of sS once (tile (0,1) is permanently masked-zero; other tiles
  // are rewritten each chunk before being read)
  for (int idx = tid; idx < 640; idx += 512) ((unsigned*)sS)[idx] = 0;

  const float* __restrict__ xb = x + (size_t)b * T_ * I_;

  if (w < 4) {
    // ================= CONSUMERS =================
    const int c0  = 16 * w + sl;   // own channel (C row / h channel)
    const int vt0 = 8 * w;         // v-pack t-range
    float wOl[7], wVl[7];
#pragma unroll
    for (int jj = 0; jj < 7; ++jj) {
      wOl[jj] = Wo[c0 * 7 + jj] * L2E;
      wVl[jj] = Wv[lane * 7 + jj];
    }
    const float bO2 = bo[c0] * L2E, bV = bv[lane];
    f32x4 Cacc[4];
#pragma unroll
    for (int ct = 0; ct < 4; ++ct)
#pragma unroll
      for (int reg = 0; reg < 4; ++reg)
        Cacc[ct][reg] =
            Cin[(size_t)b * H_ * H_ + (size_t)(16 * w + 4 * quad + reg) * H_ + 16 * ct + sl];
    float nv = nin[(size_t)b * H_ * H_ + c0];
    PACK_V32(0);
    __syncthreads();  // P-2
    __syncthreads();  // P-1
    for (int j = 0; j < NC_; ++j) {
      const int p = j & 1;
      const float* xc = xb + (size_t)j * LC_ * I_;
      // ---- region A: den-scan (own channel; fs = 2^ls, same bf16 ls as S) ----
      float den8[8];
#pragma unroll
      for (int t = 0; t < 32; ++t) {
        const float fs = ex2(bf2f(sLs[p][t][c0]));
        const float ik = bf2f(sIK[p][t][c0]);
        nv = fmaf(fs, nv, ik);
        if (((t >> 2) & 3) == quad) den8[((t >> 4) << 2) | (t & 3)] = nv;
      }
      // ---- shared S: waves 0/2/3 compute one 16x16 tile each ----
      if (w != 1) {
        const int tt = w >> 1, ss2 = w & 1;  // w0:(0,0) w2:(1,0) w3:(1,1)
        const bf16x8 aQ0 = *(const bf16x8*)&sQt[p][16 * tt + sl][8 * quad];
        const bf16x8 aQ1 = *(const bf16x8*)&sQt[p][16 * tt + sl][32 + 8 * quad];
        const bf16x8 bK0 = *(const bf16x8*)&sKt[p][16 * ss2 + sl][8 * quad];
        const bf16x8 bK1 = *(const bf16x8*)&sKt[p][16 * ss2 + sl][32 + 8 * quad];
        f32x4 Sv = {0.f, 0.f, 0.f, 0.f};
        Sv = __builtin_amdgcn_mfma_f32_16x16x32_bf16(aQ0, bK0, Sv, 0, 0, 0);
        Sv = __builtin_amdgcn_mfma_f32_16x16x32_bf16(aQ1, bK1, Sv, 0, 0, 0);
#pragma unroll
        for (int reg = 0; reg < 4; ++reg) {
          const int t = 16 * tt + 4 * quad + reg;
          const int s = 16 * ss2 + sl;
          sS[t][s] = f2bf((s <= t) ? Sv[reg] : 0.f);
        }
      }
      // ---- C0 snapshot + decay + G = V k^T (K=32 full) ----
      const bf16x8 aV = *(const bf16x8*)&sVT[p][c0][8 * quad];
#pragma unroll
      for (int ct = 0; ct < 4; ++ct) {
        const int cc = 16 * ct + sl;
        const float em = sEM[p][cc];
        const float ft = sFtot[p][cc];
#pragma unroll
        for (int reg = 0; reg < 4; ++reg)
          sC0[16 * w + 4 * quad + reg][cc] = f2bf(Cacc[ct][reg] * em);
        Cacc[ct] *= ft;
        const bf16x8 bKn = *(const bf16x8*)&sKnT[p][cc][8 * quad];
        Cacc[ct] = __builtin_amdgcn_mfma_f32_16x16x32_bf16(aV, bKn, Cacc[ct], 0, 0, 0);
      }
      if (j + 1 < NC_) PACK_V32(j + 1);
      __syncthreads();  // B1
      // ---- region B: Num (2 t-tiles) + o + h ----
      const bf16x8 bC0a = *(const bf16x8*)&sC0[c0][8 * quad];
      const bf16x8 bC0b = *(const bf16x8*)&sC0[c0][32 + 8 * quad];
#pragma unroll
      for (int tt = 0; tt < 2; ++tt) {
        const bf16x8 aQ0 = *(const bf16x8*)&sQt[p][16 * tt + sl][8 * quad];
        const bf16x8 aQ1 = *(const bf16x8*)&sQt[p][16 * tt + sl][32 + 8 * quad];
        const bf16x8 aS  = *(const bf16x8*)&sS[16 * tt + sl][8 * quad];
        f32x4 Num = {0.f, 0.f, 0.f, 0.f};
        Num = __builtin_amdgcn_mfma_f32_16x16x32_bf16(aQ0, bC0a, Num, 0, 0, 0);
        Num = __builtin_amdgcn_mfma_f32_16x16x32_bf16(aQ1, bC0b, Num, 0, 0, 0);
        Num = __builtin_amdgcn_mfma_f32_16x16x32_bf16(aS, aV, Num, 0, 0, 0);
#pragma unroll
        for (int reg = 0; reg < 4; ++reg) {
          const int t = 16 * tt + 4 * quad + reg;
          const float den = den8[tt * 4 + reg];
          const float idn = __fdividef(1.f, fmaxf(den * sSq[p][t], 1.f));
          float op = bO2;
#pragma unroll
          for (int jj = 0; jj < 7; ++jj) op = fmaf(xc[t * 7 + jj], wOl[jj], op);
          const float o = sig2(op);
          const float y = Num[reg] * idn;
          const float e = ex2(y * 2.88539008178f);  // e^{2y}
          const float th = 1.f - __fdividef(2.f, e + 1.f);
          hout[(size_t)b * T_ * H_ + (size_t)(j * LC_ + t) * H_ + c0] = o * th;
        }
      }
      __syncthreads();  // B2
    }
#pragma unroll
    for (int ct = 0; ct < 4; ++ct)
#pragma unroll
      for (int reg = 0; reg < 4; ++reg)
        Cout[(size_t)b * H_ * H_ + (size_t)(16 * w + 4 * quad + reg) * H_ + 16 * ct + sl] =
            Cacc[ct][reg];
    if (quad == 0) sNv[c0] = nv;
  } else if (w == 4 || w == 5) {
    // ================= i*k producer (t-half tb) =================
    const int tb = (w == 4) ? 0 : 16;
    float wi2[7], wk[7];
#pragma unroll
    for (int jj = 0; jj < 7; ++jj) {
      wi2[jj] = Wi[lane * 7 + jj] * L2E;
      wk[jj]  = Wk[lane * 7 + jj];
    }
    const float bI2 = bi[lane] * L2E, bK = bk[lane];
    IK_PRE32(0);
    __syncthreads();  // P-2
    IK_EXP32(0);
    __syncthreads();  // P-1
    for (int j = 0; j < NC_; ++j) {
      if (j + 1 < NC_) IK_PRE32(j + 1);
      __syncthreads();  // B1
      if (j + 1 < NC_) IK_EXP32(j + 1);
      __syncthreads();  // B2
    }
  } else if (w == 6) {
    // ================= f-half (t0-15) + scalars + q~ lo =================
    const int ftb = 0;
    float wf2[7], wq[7];
#pragma unroll
    for (int jj = 0; jj < 7; ++jj) {
      wf2[jj] = Wf[lane * 7 + jj] * L2E;
      wq[jj]  = Wq[lane * 7 + jj];
    }
    const float bF2 = bf[lane] * L2E, bQ = bq[lane];
    F_HALF32(0);
    __syncthreads();  // P-2
    SCALQ32(0);
    __syncthreads();  // P-1
    for (int j = 0; j < NC_; ++j) {
      if (j + 1 < NC_) F_HALF32(j + 1);
      __syncthreads();  // B1
      if (j + 1 < NC_) SCALQ32(j + 1);
      __syncthreads();  // B2
    }
  } else {
    // ================= f-half (t16-31) + q~ hi + Sq =================
    const int ftb = 16;
    float wf2[7], wq[7], wqs[8];
#pragma unroll
    for (int jj = 0; jj < 7; ++jj) {
      wf2[jj] = Wf[lane * 7 + jj] * L2E;
      wq[jj]  = Wq[lane * 7 + jj];
    }
    const float bF2 = bf[lane] * L2E, bQ = bq[lane];
#pragma unroll
    for (int jj = 0; jj < 7; ++jj) {
      float s = wq[jj];
#pragma unroll
      for (int off = 32; off >= 1; off >>= 1) s += __shfl_xor(s, off);
      wqs[jj] = s;
    }
    {
      float s = bQ;
#pragma unroll
      for (int off = 32; off >= 1; off >>= 1) s += __shfl_xor(s, off);
      wqs[7] = s;
    }
    F_HALF32(0);
    __syncthreads();  // P-2
    SQQ32(0);
    __syncthreads();  // P-1
    for (int j = 0; j < NC_; ++j) {
      if (j + 1 < NC_) F_HALF32(j + 1);
      __syncthreads();  // B1
      if (j + 1 < NC_) SQQ32(j + 1);
      __syncthreads();  // B2
    }
  }

  __syncthreads();  // final: sNv ready
  {
    const float nvv = sNv[lane];
#pragma unroll
    for (int k = 0; k < 8; ++k)
      nout[(size_t)b * H_ * H_ + (size_t)(8 * w + k) * H_ + lane] = nvv;
  }
}

extern "C" void kernel_launch(void* const* d_in, const int* in_sizes, int n_in,
                              void* d_out, int out_size, void* d_ws, size_t ws_size,
                              hipStream_t stream) {
  const float* xp  = (const float*)d_in[0];
  const float* Cp  = (const float*)d_in[1];
  const float* np_ = (const float*)d_in[2];

  const float* W[6];
  const float* Bv[6];
  if (n_in >= 15 && in_sizes[4] == 64) {
    for (int g = 0; g < 6; ++g) {
      W[g]  = (const float*)d_in[3 + 2 * g];
      Bv[g] = (const float*)d_in[4 + 2 * g];
    }
  } else {
    for (int g = 0; g < 6; ++g) {
      W[g]  = (const float*)d_in[3 + g];
      Bv[g] = (const float*)d_in[9 + g];
    }
  }

  float* hout = (float*)d_out;
  float* Cout = hout + (size_t)B_ * T_ * H_;
  float* nout = Cout + (size_t)B_ * H_ * H_;

  mlstm32<<<dim3(B_), dim3(512), 0, stream>>>(
      xp, Cp, np_,
      W[0], Bv[0], W[1], Bv[1], W[2], Bv[2],
      W[3], Bv[3], W[4], Bv[4], W[5], Bv[5],
      hout, Cout, nout);
}

// Round 12
// 141.669 us; speedup vs baseline: 1.1862x; 1.1862x over previous
//
#include <hip/hip_runtime.h>
#include <math.h>

#define B_ 512
#define T_ 256
#define I_ 7
#define H_ 64
#define L_ 16
#define NCH_ (T_ / L_)
#define L2E 1.44269504089f
#define GUARD2 (-21.64f)

typedef short bf16x8 __attribute__((ext_vector_type(8)));
typedef short short4v __attribute__((ext_vector_type(4)));
typedef float f32x4 __attribute__((ext_vector_type(4)));

__device__ __forceinline__ unsigned short f2bf(float f) {
  unsigned u = __float_as_uint(f);
  u += 0x7fff + ((u >> 16) & 1);          // RNE
  return (unsigned short)(u >> 16);
}
__device__ __forceinline__ float bf2f(unsigned short u) {
  return __uint_as_float(((unsigned)u) << 16);
}
__device__ __forceinline__ float ex2(float x) { return __builtin_amdgcn_exp2f(x); }
__device__ __forceinline__ float lg2(float x) { return __builtin_amdgcn_logf(x); }
// log2(sigmoid(a)) given a already scaled by log2e
__device__ __forceinline__ float logsig2(float a2) {
  return (a2 < GUARD2) ? a2 : -lg2(1.f + ex2(-a2));
}
__device__ __forceinline__ float sig2(float a2) {
  return __fdividef(1.f, 1.f + ex2(-a2));
}

// ---- pack waves (chunk C, t-half th0): v on w8/w9, o on w10/w11 ----
#define PACK_V(C) do {                                                        \
  const float* xp_ = xb + (C) * (L_ * I_);                                    \
  unsigned short vv[8];                                                       \
  _Pragma("unroll") for (int tt = 0; tt < 8; ++tt) {                          \
    const int t = th0 + tt;                                                   \
    float vp = bP;                                                            \
    _Pragma("unroll") for (int jj = 0; jj < 7; ++jj)                          \
      vp = fmaf(xp_[t * 7 + jj], wP[jj], vp);                                 \
    vv[tt] = f2bf(vp);                                                        \
  }                                                                           \
  short4v p0 = {(short)vv[0], (short)vv[1], (short)vv[2], (short)vv[3]};      \
  short4v p1 = {(short)vv[4], (short)vv[5], (short)vv[6], (short)vv[7]};      \
  *(short4v*)&sVT[(C) & 1][lane][th0]     = p0;                               \
  *(short4v*)&sVT[(C) & 1][lane][th0 + 4] = p1;                               \
} while (0)

#define PACK_O(C) do {                                                        \
  const float* xp_ = xb + (C) * (L_ * I_);                                    \
  _Pragma("unroll") for (int tt = 0; tt < 8; ++tt) {                          \
    const int t = th0 + tt;                                                   \
    float op = bP;                                                            \
    _Pragma("unroll") for (int jj = 0; jj < 7; ++jj)                          \
      op = fmaf(xp_[t * 7 + jj], wP[jj], op);                                 \
    sOpre[(C) & 1][t][lane] = f2bf(op);                                       \
  }                                                                           \
} while (0)

// ---- w4/w5: i*k preacts + ik (t-half tb) ----
#define IK_PRE(C) do {                                                        \
  const float* xp_ = xb + (C) * (L_ * I_);                                    \
  _Pragma("unroll") for (int tt = 0; tt < 8; ++tt) {                          \
    const int t = tb + tt;                                                    \
    float xs[7];                                                              \
    _Pragma("unroll") for (int jj = 0; jj < 7; ++jj) xs[jj] = xp_[t * 7 + jj];\
    float ip = bI2, kp = bK;                                                  \
    _Pragma("unroll") for (int jj = 0; jj < 7; ++jj) {                        \
      ip = fmaf(xs[jj], wi2[jj], ip);                                         \
      kp = fmaf(xs[jj], wk[jj], kp);                                          \
    }                                                                         \
    const float ik = ex2(ip) * kp * 0.125f;                                   \
    ik8[tt] = ik;                                                             \
    sIK[(C) & 1][t][lane] = ik;                                               \
  }                                                                           \
} while (0)

// ---- w4/w5: k~ = ik*2^{m-cl}, k^ = ik*2^{cl15-cl} (prefix from sLs) ----
#define IK_EXP(C) do {                                                        \
  float cl[16];                                                               \
  _Pragma("unroll") for (int t = 0; t < 16; ++t) cl[t] = sLs[(C) & 1][lane][t]; \
  _Pragma("unroll") for (int t = 1; t < 16; ++t) cl[t] += cl[t - 1];          \
  const float m = cl[7];                                                      \
  const float scl = ex2(cl[15] - m);                                          \
  unsigned short kh[8];                                                       \
  _Pragma("unroll") for (int tt = 0; tt < 8; ++tt) {                          \
    const int t = tb + tt;                                                    \
    const float u = ik8[tt] * ex2(m - cl[t]);                                 \
    sKt[(C) & 1][t][lane] = f2bf(u);                                          \
    kh[tt] = f2bf(u * scl);                                                   \
  }                                                                           \
  short4v p0 = {(short)kh[0], (short)kh[1], (short)kh[2], (short)kh[3]};      \
  short4v p1 = {(short)kh[4], (short)kh[5], (short)kh[6], (short)kh[7]};      \
  *(short4v*)&sKnT[(C) & 1][lane][tb]     = p0;                               \
  *(short4v*)&sKnT[(C) & 1][lane][tb + 4] = p1;                               \
} while (0)

// ---- w6/w7: f-gate half (t = ftb..ftb+7) -> sLs ----
#define F_HALF(C) do {                                                        \
  const float* xp_ = xb + (C) * (L_ * I_);                                    \
  _Pragma("unroll") for (int tt = 0; tt < 8; ++tt) {                          \
    const int t = ftb + tt;                                                   \
    float fp = bF2;                                                           \
    _Pragma("unroll") for (int jj = 0; jj < 7; ++jj)                          \
      fp = fmaf(xp_[t * 7 + jj], wf2[jj], fp);                                \
    sLs[(C) & 1][lane][t] = logsig2(fp);                                      \
  }                                                                           \
} while (0)

// ---- w6: chunk scalars (2^{cl7}, 2^{cl15}) + Sq + q~ for t0-7 ----
#define SCALQ(C) do {                                                         \
  const float* xp_ = xb + (C) * (L_ * I_);                                    \
  float cl[16];                                                               \
  _Pragma("unroll") for (int t = 0; t < 16; ++t) cl[t] = sLs[(C) & 1][lane][t]; \
  _Pragma("unroll") for (int t = 1; t < 16; ++t) cl[t] += cl[t - 1];          \
  sEM[(C) & 1][lane]   = ex2(cl[7]);                                          \
  sFtot[(C) & 1][lane] = ex2(cl[15]);                                         \
  if (lane < 16) {                                                            \
    float Sqv = wqs[7];                                                       \
    _Pragma("unroll") for (int jj = 0; jj < 7; ++jj)                          \
      Sqv = fmaf(xp_[lane * 7 + jj], wqs[jj], Sqv);                           \
    sSq[(C) & 1][lane] = Sqv;                                                 \
  }                                                                           \
  const float m = cl[7];                                                      \
  _Pragma("unroll") for (int t = 0; t < 8; ++t) {                             \
    float qq = bQ;                                                            \
    _Pragma("unroll") for (int jj = 0; jj < 7; ++jj)                          \
      qq = fmaf(xp_[t * 7 + jj], wq[jj], qq);                                 \
    sQt[(C) & 1][t][lane] = f2bf(qq * ex2(cl[t] - m));                        \
  }                                                                           \
} while (0)

// ---- w7: den-scan (exact fp32, fs = 2^ls) + q~ for t8-15 ----
#define QDEN(C) do {                                                          \
  const float* xp_ = xb + (C) * (L_ * I_);                                    \
  float ls[16], cl[16];                                                       \
  _Pragma("unroll") for (int t = 0; t < 16; ++t) ls[t] = sLs[(C) & 1][lane][t]; \
  _Pragma("unroll") for (int t = 0; t < 16; ++t) {                            \
    nv = fmaf(ex2(ls[t]), nv, sIK[(C) & 1][t][lane]);                         \
    sDen[(C) & 1][t][lane] = nv;                                              \
  }                                                                           \
  cl[0] = ls[0];                                                              \
  _Pragma("unroll") for (int t = 1; t < 16; ++t) cl[t] = cl[t - 1] + ls[t];   \
  const float m = cl[7];                                                      \
  _Pragma("unroll") for (int t = 8; t < 16; ++t) {                            \
    float qq = bQ;                                                            \
    _Pragma("unroll") for (int jj = 0; jj < 7; ++jj)                          \
      qq = fmaf(xp_[t * 7 + jj], wq[jj], qq);                                 \
    sQt[(C) & 1][t][lane] = f2bf(qq * ex2(cl[t] - m));                        \
  }                                                                           \
} while (0)

// R9's proven structure + 4 dedicated pack waves: 768 threads = 12 waves.
// w0-3: PURE consumers (P2 | P3+h). w4/5: ik halves. w6: f-lo + scalars/Sq/q~lo.
// w7: f-hi + den-scan + q~hi. w8/9: v-pack halves (region A). w10/11: o-pack
// halves (region B). Same LDS, same barrier parities as R9 (all cross-wave
// deps cross >=1 barrier). 2 blocks/CU x 12 waves = 24 waves/CU (6/SIMD, was
// 4/SIMD) -- the TLP lever: R9's regions are 45% issue / 55% un-hidden stall.
// Roles are disjoint branches -> VGPR stays ~52 (no union spill, R8 lesson).
// sS fully zeroed once (bf16 junk can be NaN; NaN*0=NaN through MFMA -- R4).
__global__ __launch_bounds__(768, 6) void mlstm_w12(
    const float* __restrict__ x,
    const float* __restrict__ Cin,
    const float* __restrict__ nin,
    const float* __restrict__ Wq, const float* __restrict__ bq,
    const float* __restrict__ Wk, const float* __restrict__ bk,
    const float* __restrict__ Wv, const float* __restrict__ bv,
    const float* __restrict__ Wi, const float* __restrict__ bi,
    const float* __restrict__ Wf, const float* __restrict__ bf,
    const float* __restrict__ Wo, const float* __restrict__ bo,
    float* __restrict__ hout, float* __restrict__ Cout, float* __restrict__ nout)
{
  const int b    = blockIdx.x;
  const int tid  = threadIdx.x;
  const int lane = tid & 63;
  const int w    = __builtin_amdgcn_readfirstlane(tid >> 6);  // wave 0..11
  const int quad = lane >> 4;
  const int sl   = lane & 15;

  __shared__ __align__(16) unsigned short sQt[2][L_][72];   // q~ [t][c]
  __shared__ __align__(16) unsigned short sKt[2][L_][72];   // k~ [s][c]
  __shared__ __align__(16) unsigned short sKnT[2][H_][40];  // k^T [c][s] (s16..31 = 0)
  __shared__ __align__(16) unsigned short sVT[2][H_][40];   // v [r][s]   (s16..31 = 0)
  __shared__ __align__(16) unsigned short sS[4][L_][32];    // private masked S (16..31 = 0)
  __shared__ __align__(16) unsigned short sC0[H_][72];      // C0*2^m [r][c] (same-wave)
  __shared__ __align__(16) unsigned short sOpre[2][L_][72]; // o preact (base-2) [t][c]
  __shared__ float sDen[2][L_][68];  // n-scan value [t][c]
  __shared__ float sIK[2][L_][H_];   // i*k (scaled) [t][c]
  __shared__ float sLs[2][H_][17];   // log2(sigmoid(f)) [c][t]
  __shared__ float sSq[2][L_];       // sum_r q_t[r]
  __shared__ float sEM[2][H_];       // 2^{cl7}
  __shared__ float sFtot[2][H_];     // 2^{cl15}
  __shared__ float sNv[H_];

  // zero pads: sKnT/sVT cols 16..31 (both buffers), ALL of sS
  for (int idx = tid; idx < 1024; idx += 768) {
    const int r = idx >> 3, d = idx & 7;
    ((unsigned*)sKnT)[r * 20 + 8 + d] = 0;
    ((unsigned*)sVT)[r * 20 + 8 + d]  = 0;
  }
  for (int idx = tid; idx < 1024; idx += 768) ((unsigned*)sS)[idx] = 0;

  const float* __restrict__ xb = x + (size_t)b * T_ * I_;

  if (w < 4) {
    // ============ PURE CONSUMERS ============
    const int c0 = 16 * w + sl;
    f32x4 Cacc[4];
#pragma unroll
    for (int ct = 0; ct < 4; ++ct)
#pragma unroll
      for (int reg = 0; reg < 4; ++reg)
        Cacc[ct][reg] =
            Cin[(size_t)b * H_ * H_ + (size_t)(16 * w + 4 * quad + reg) * H_ + 16 * ct + sl];
    __syncthreads();  // B0a
    __syncthreads();  // B0b
    for (int j = 0; j < NCH_; ++j) {
      const int p = j & 1;
      // ---- region A: P2 ----
      const bf16x8 aQ0 = *(const bf16x8*)&sQt[p][sl][8 * quad];
      const bf16x8 aQ1 = *(const bf16x8*)&sQt[p][sl][32 + 8 * quad];
      const bf16x8 bK0 = *(const bf16x8*)&sKt[p][sl][8 * quad];
      const bf16x8 bK1 = *(const bf16x8*)&sKt[p][sl][32 + 8 * quad];
      f32x4 Sv = {0.f, 0.f, 0.f, 0.f};
      Sv = __builtin_amdgcn_mfma_f32_16x16x32_bf16(aQ0, bK0, Sv, 0, 0, 0);
      Sv = __builtin_amdgcn_mfma_f32_16x16x32_bf16(aQ1, bK1, Sv, 0, 0, 0);
#pragma unroll
      for (int reg = 0; reg < 4; ++reg) {
        const int t = 4 * quad + reg;
        sS[w][t][sl] = f2bf((sl <= t) ? Sv[reg] : 0.f);
      }
      const bf16x8 aV = *(const bf16x8*)&sVT[p][c0][8 * quad];
#pragma unroll
      for (int ct = 0; ct < 4; ++ct) {
        const int cc = 16 * ct + sl;
        const float em = sEM[p][cc];
        const float ft = sFtot[p][cc];
#pragma unroll
        for (int reg = 0; reg < 4; ++reg)
          sC0[16 * w + 4 * quad + reg][cc] = f2bf(Cacc[ct][reg] * em);
        Cacc[ct] *= ft;
        const bf16x8 bH = *(const bf16x8*)&sKnT[p][cc][8 * quad];
        Cacc[ct] = __builtin_amdgcn_mfma_f32_16x16x32_bf16(aV, bH, Cacc[ct], 0, 0, 0);
      }
      __syncthreads();  // B1
      // ---- region B: P3 + h ----
      const bf16x8 bC0a = *(const bf16x8*)&sC0[c0][8 * quad];
      const bf16x8 bC0b = *(const bf16x8*)&sC0[c0][32 + 8 * quad];
      const bf16x8 aS   = *(const bf16x8*)&sS[w][sl][8 * quad];
      f32x4 Num = {0.f, 0.f, 0.f, 0.f};
      Num = __builtin_amdgcn_mfma_f32_16x16x32_bf16(aQ0, bC0a, Num, 0, 0, 0);
      Num = __builtin_amdgcn_mfma_f32_16x16x32_bf16(aQ1, bC0b, Num, 0, 0, 0);
      Num = __builtin_amdgcn_mfma_f32_16x16x32_bf16(aS, aV, Num, 0, 0, 0);
#pragma unroll
      for (int reg = 0; reg < 4; ++reg) {
        const int t = 4 * quad + reg;
        const float den = sDen[p][t][c0];
        const float idn = __fdividef(1.f, fmaxf(den * sSq[p][t], 1.f));
        const float o   = sig2(bf2f(sOpre[p][t][c0]));
        const float y = Num[reg] * idn;
        const float e = ex2(y * 2.88539008178f);  // e^{2y}
        const float th = 1.f - __fdividef(2.f, e + 1.f);
        hout[(size_t)b * T_ * H_ + (size_t)(j * L_ + t) * H_ + c0] = o * th;
      }
      __syncthreads();  // B2
    }
#pragma unroll
    for (int ct = 0; ct < 4; ++ct)
#pragma unroll
      for (int reg = 0; reg < 4; ++reg)
        Cout[(size_t)b * H_ * H_ + (size_t)(16 * w + 4 * quad + reg) * H_ + 16 * ct + sl] =
            Cacc[ct][reg];
  } else if (w == 4 || w == 5) {
    // ============ i*k producer (t-half tb) ============
    const int tb = (w == 4) ? 0 : 8;
    float wi2[7], wk[7];
#pragma unroll
    for (int jj = 0; jj < 7; ++jj) {
      wi2[jj] = Wi[lane * 7 + jj] * L2E;
      wk[jj]  = Wk[lane * 7 + jj];
    }
    const float bI2 = bi[lane] * L2E, bK = bk[lane];
    float ik8[8];
    IK_PRE(0);
    __syncthreads();  // B0a
    IK_EXP(0);
    __syncthreads();  // B0b
    for (int j = 0; j < NCH_; ++j) {
      if (j + 1 < NCH_) IK_PRE(j + 1);
      __syncthreads();  // B1
      if (j + 1 < NCH_) IK_EXP(j + 1);
      __syncthreads();  // B2
    }
  } else if (w == 6) {
    // ============ f-half (t0-7) + chunk scalars + Sq + q~(t0-7) ============
    const int ftb = 0;
    float wf2[7], wq[7], wqs[8];
#pragma unroll
    for (int jj = 0; jj < 7; ++jj) {
      wf2[jj] = Wf[lane * 7 + jj] * L2E;
      wq[jj]  = Wq[lane * 7 + jj];
    }
    const float bF2 = bf[lane] * L2E, bQ = bq[lane];
#pragma unroll
    for (int jj = 0; jj < 7; ++jj) {
      float s = wq[jj];
#pragma unroll
      for (int off = 32; off >= 1; off >>= 1) s += __shfl_xor(s, off);
      wqs[jj] = s;
    }
    {
      float s = bQ;
#pragma unroll
      for (int off = 32; off >= 1; off >>= 1) s += __shfl_xor(s, off);
      wqs[7] = s;
    }
    F_HALF(0);
    __syncthreads();  // B0a
    SCALQ(0);
    __syncthreads();  // B0b
    for (int j = 0; j < NCH_; ++j) {
      if (j + 1 < NCH_) F_HALF(j + 1);
      __syncthreads();  // B1
      if (j + 1 < NCH_) SCALQ(j + 1);
      __syncthreads();  // B2
    }
  } else if (w == 7) {
    // ============ f-half (t8-15) + den-scan + q~(t8-15) ============
    const int ftb = 8;
    float wf2[7], wq[7];
#pragma unroll
    for (int jj = 0; jj < 7; ++jj) {
      wf2[jj] = Wf[lane * 7 + jj] * L2E;
      wq[jj]  = Wq[lane * 7 + jj];
    }
    const float bF2 = bf[lane] * L2E, bQ = bq[lane];
    float nv = nin[(size_t)b * H_ * H_ + lane];
    F_HALF(0);
    __syncthreads();  // B0a
    QDEN(0);
    __syncthreads();  // B0b
    for (int j = 0; j < NCH_; ++j) {
      if (j + 1 < NCH_) F_HALF(j + 1);
      __syncthreads();  // B1
      if (j + 1 < NCH_) QDEN(j + 1);
      __syncthreads();  // B2
    }
    sNv[lane] = nv;
  } else if (w == 8 || w == 9) {
    // ============ v-pack (t-half), region A ============
    const int th0 = (w == 8) ? 0 : 8;
    float wP[7];
#pragma unroll
    for (int jj = 0; jj < 7; ++jj) wP[jj] = Wv[lane * 7 + jj];
    const float bP = bv[lane];
    PACK_V(0);
    __syncthreads();  // B0a
    __syncthreads();  // B0b
    for (int j = 0; j < NCH_; ++j) {
      if (j + 1 < NCH_) PACK_V(j + 1);
      __syncthreads();  // B1
      __syncthreads();  // B2
    }
  } else {
    // ============ o-pack (t-half), region B ============
    const int th0 = (w == 10) ? 0 : 8;
    float wP[7];
#pragma unroll
    for (int jj = 0; jj < 7; ++jj) wP[jj] = Wo[lane * 7 + jj] * L2E;
    const float bP = bo[lane] * L2E;
    PACK_O(0);
    __syncthreads();  // B0a
    __syncthreads();  // B0b
    for (int j = 0; j < NCH_; ++j) {
      __syncthreads();  // B1
      if (j + 1 < NCH_) PACK_O(j + 1);
      __syncthreads();  // B2
    }
  }

  __syncthreads();  // final: sNv ready
  if (w < 8) {
    const float nvv = sNv[lane];
#pragma unroll
    for (int k = 0; k < 8; ++k)
      nout[(size_t)b * H_ * H_ + (size_t)(8 * w + k) * H_ + lane] = nvv;
  }
}

extern "C" void kernel_launch(void* const* d_in, const int* in_sizes, int n_in,
                              void* d_out, int out_size, void* d_ws, size_t ws_size,
                              hipStream_t stream) {
  const float* xp  = (const float*)d_in[0];
  const float* Cp  = (const float*)d_in[1];
  const float* np_ = (const float*)d_in[2];

  const float* W[6];
  const float* Bv[6];
  if (n_in >= 15 && in_sizes[4] == 64) {
    for (int g = 0; g < 6; ++g) {
      W[g]  = (const float*)d_in[3 + 2 * g];
      Bv[g] = (const float*)d_in[4 + 2 * g];
    }
  } else {
    for (int g = 0; g < 6; ++g) {
      W[g]  = (const float*)d_in[3 + g];
      Bv[g] = (const float*)d_in[9 + g];
    }
  }

  float* hout = (float*)d_out;
  float* Cout = hout + (size_t)B_ * T_ * H_;
  float* nout = Cout + (size_t)B_ * H_ * H_;

  mlstm_w12<<<dim3(B_), dim3(768), 0, stream>>>(
      xp, Cp, np_,
      W[0], Bv[0], W[1], Bv[1], W[2], Bv[2],
      W[3], Bv[3], W[4], Bv[4], W[5], Bv[5],
      hout, Cout, nout);
}